// Round 3
// baseline (736.749 us; speedup 1.0000x reference)
//
#include <hip/hip_runtime.h>
#include <hip/hip_bf16.h>
#include <stdint.h>

#define D_DIM 128
#define IN_FEAT 1024
#define OUT_FEAT 1024
#define N_ROWS 4096

typedef __attribute__((ext_vector_type(8))) short short8;
typedef __attribute__((ext_vector_type(4))) float f32x4;

// ---------------- Kernel 1: synthesize A[o,i] = sum_d theta_d[d]*P_A[o,d,i] + theta0_A[o,i], store bf16
// Memory-bound: streams 512 MB of P_A once, coalesced float4 per lane.
__global__ __launch_bounds__(256) void synth_A_kernel(
    const float* __restrict__ theta_d, const float* __restrict__ theta0_A,
    const float* __restrict__ P_A, __hip_bfloat16* __restrict__ A_bf)
{
    int t  = blockIdx.x * 256 + threadIdx.x;   // 0..262143, one thread per 4 outputs
    int o  = t >> 8;                            // 0..1023
    int i4 = (t & 255) << 2;                    // 0..1020

    const float4* p = reinterpret_cast<const float4*>(P_A + (size_t)o * (D_DIM * IN_FEAT) + i4);
    float4 t0 = *reinterpret_cast<const float4*>(theta0_A + (size_t)o * IN_FEAT + i4);
    float ax = t0.x, ay = t0.y, az = t0.z, aw = t0.w;

#pragma unroll 8
    for (int d = 0; d < D_DIM; ++d) {
        float td  = theta_d[d];                 // uniform -> scalar load
        float4 pv = p[(size_t)d * (IN_FEAT / 4)];
        ax = fmaf(td, pv.x, ax); ay = fmaf(td, pv.y, ay);
        az = fmaf(td, pv.z, az); aw = fmaf(td, pv.w, aw);
    }

    union { __hip_bfloat16 h[4]; ushort4 u; } cv;
    cv.h[0] = __float2bfloat16(ax); cv.h[1] = __float2bfloat16(ay);
    cv.h[2] = __float2bfloat16(az); cv.h[3] = __float2bfloat16(aw);
    *reinterpret_cast<ushort4*>(A_bf + (size_t)o * IN_FEAT + i4) = cv.u;
}

// ---------------- Kernel 2: cast x fp32 -> bf16
__global__ __launch_bounds__(256) void cast_x_kernel(
    const float* __restrict__ x, __hip_bfloat16* __restrict__ xb)
{
    int t = blockIdx.x * 256 + threadIdx.x;     // one thread per 4 elements
    float4 v = reinterpret_cast<const float4*>(x)[t];
    union { __hip_bfloat16 h[4]; ushort4 u; } cv;
    cv.h[0] = __float2bfloat16(v.x); cv.h[1] = __float2bfloat16(v.y);
    cv.h[2] = __float2bfloat16(v.z); cv.h[3] = __float2bfloat16(v.w);
    reinterpret_cast<ushort4*>(xb)[t] = cv.u;
}

// ---------------- Kernel 3: bias b[o] = sum_d theta_d[d]*P_b[d,o] + theta0_b[o] (fp32)
__global__ __launch_bounds__(256) void synth_b_kernel(
    const float* __restrict__ theta_d, const float* __restrict__ theta0_b,
    const float* __restrict__ P_b, float* __restrict__ bias)
{
    int o = blockIdx.x * 256 + threadIdx.x;     // 1024 threads
    float acc = theta0_b[o];
#pragma unroll 8
    for (int d = 0; d < D_DIM; ++d)
        acc = fmaf(theta_d[d], P_b[(size_t)d * OUT_FEAT + o], acc);
    bias[o] = acc;
}

// ---------------- Kernel 4: out[m,n] = sum_k Xb[m,k]*Wb[n,k] + bias[n]
// 128x128 tile, BK=64, 4 waves (2x2), each wave 64x64 via 4x4 16x16x32 MFMA frags.
// Staging: global_load_lds width=16 (linear LDS dest), XOR-chunk swizzle applied on the
// GLOBAL source (rule 21) and re-applied on the ds_read address -> 2-way (free) bank access.
#define BM 128
#define BN 128
#define BK 64

__global__ __launch_bounds__(256) void gemm_kernel(
    const __hip_bfloat16* __restrict__ Xb, const __hip_bfloat16* __restrict__ Wb,
    const float* __restrict__ bias, float* __restrict__ out)
{
    __shared__ __hip_bfloat16 As[BM * BK];   // 16 KB
    __shared__ __hip_bfloat16 Bs[BN * BK];   // 16 KB

    const int tid  = threadIdx.x;
    const int lane = tid & 63;
    const int w    = tid >> 6;
    const int wr   = w >> 1;     // 0..1
    const int wc   = w & 1;      // 0..1
    const int l15  = lane & 15;
    const int l4   = lane >> 4;

    const int bm0 = blockIdx.y * BM;
    const int bn0 = blockIdx.x * BN;

    f32x4 acc[4][4];
#pragma unroll
    for (int mi = 0; mi < 4; ++mi)
#pragma unroll
        for (int ni = 0; ni < 4; ++ni)
            acc[mi][ni] = (f32x4){0.f, 0.f, 0.f, 0.f};

    for (int k0 = 0; k0 < IN_FEAT; k0 += BK) {
        // ---- stage A and B tiles (4 rounds each, 16 B per thread per round)
#pragma unroll
        for (int p = 0; p < 4; ++p) {
            int s     = p * 256 + tid;          // linear 16B slot, 0..1023
            int r     = s >> 3;                 // tile row 0..127
            int cphys = s & 7;                  // physical 16B chunk in row
            int clog  = cphys ^ (r & 7);        // pre-swizzled source chunk
            const __hip_bfloat16* gA = Xb + (size_t)(bm0 + r) * IN_FEAT + k0 + clog * 8;
            const __hip_bfloat16* gB = Wb + (size_t)(bn0 + r) * IN_FEAT + k0 + clog * 8;
            __builtin_amdgcn_global_load_lds(
                (const __attribute__((address_space(1))) unsigned int*)gA,
                (__attribute__((address_space(3))) unsigned int*)(As + s * 8), 16, 0, 0);
            __builtin_amdgcn_global_load_lds(
                (const __attribute__((address_space(1))) unsigned int*)gB,
                (__attribute__((address_space(3))) unsigned int*)(Bs + s * 8), 16, 0, 0);
        }
        __syncthreads();   // compiler drains vmcnt before s_barrier

        // ---- fragment loads (swizzled ds_read_b128) + MFMA
        short8 af[4][2], bfr[4][2];
#pragma unroll
        for (int mi = 0; mi < 4; ++mi)
#pragma unroll
            for (int kk = 0; kk < 2; ++kk) {
                int row   = wr * 64 + mi * 16 + l15;
                int chunk = (kk * 4 + l4) ^ (row & 7);
                af[mi][kk] = *reinterpret_cast<const short8*>(As + row * BK + chunk * 8);
            }
#pragma unroll
        for (int ni = 0; ni < 4; ++ni)
#pragma unroll
            for (int kk = 0; kk < 2; ++kk) {
                int row   = wc * 64 + ni * 16 + l15;
                int chunk = (kk * 4 + l4) ^ (row & 7);
                bfr[ni][kk] = *reinterpret_cast<const short8*>(Bs + row * BK + chunk * 8);
            }
#pragma unroll
        for (int mi = 0; mi < 4; ++mi)
#pragma unroll
            for (int ni = 0; ni < 4; ++ni)
#pragma unroll
                for (int kk = 0; kk < 2; ++kk)
                    acc[mi][ni] = __builtin_amdgcn_mfma_f32_16x16x32_bf16(
                        af[mi][kk], bfr[ni][kk], acc[mi][ni], 0, 0, 0);
        __syncthreads();
    }

    // ---- epilogue: C/D layout col=lane&15, row=(lane>>4)*4+j  [m89-verified]
#pragma unroll
    for (int mi = 0; mi < 4; ++mi)
#pragma unroll
        for (int ni = 0; ni < 4; ++ni) {
            int gm = bm0 + wr * 64 + mi * 16 + l4 * 4;
            int gn = bn0 + wc * 64 + ni * 16 + l15;
            float bv = bias[gn];
            f32x4 v = acc[mi][ni];
#pragma unroll
            for (int j = 0; j < 4; ++j)
                out[(size_t)(gm + j) * OUT_FEAT + gn] = v[j] + bv;
        }
}

extern "C" void kernel_launch(void* const* d_in, const int* in_sizes, int n_in,
                              void* d_out, int out_size, void* d_ws, size_t ws_size,
                              hipStream_t stream)
{
    const float* x        = (const float*)d_in[0];
    const float* theta_d  = (const float*)d_in[1];
    const float* theta0_A = (const float*)d_in[2];
    const float* P_A      = (const float*)d_in[3];
    const float* theta0_b = (const float*)d_in[4];
    const float* P_b      = (const float*)d_in[5];
    float* out            = (float*)d_out;

    char* ws = (char*)d_ws;
    __hip_bfloat16* xb   = (__hip_bfloat16*)ws;                                   // 8 MB
    __hip_bfloat16* A_bf = (__hip_bfloat16*)(ws + (size_t)N_ROWS * IN_FEAT * 2);  // 2 MB
    float* bias          = (float*)(ws + (size_t)N_ROWS * IN_FEAT * 2
                                       + (size_t)OUT_FEAT * IN_FEAT * 2);         // 4 KB

    hipLaunchKernelGGL(synth_A_kernel, dim3((OUT_FEAT * IN_FEAT / 4) / 256), dim3(256), 0, stream,
                       theta_d, theta0_A, P_A, A_bf);
    hipLaunchKernelGGL(cast_x_kernel, dim3((N_ROWS * IN_FEAT / 4) / 256), dim3(256), 0, stream,
                       x, xb);
    hipLaunchKernelGGL(synth_b_kernel, dim3(OUT_FEAT / 256), dim3(256), 0, stream,
                       theta_d, theta0_b, P_b, bias);
    hipLaunchKernelGGL(gemm_kernel, dim3(OUT_FEAT / BN, N_ROWS / BM), dim3(256), 0, stream,
                       xb, A_bf, bias, out);
}